// Round 4
// baseline (138.625 us; speedup 1.0000x reference)
//
#include <hip/hip_runtime.h>
#include <math.h>

// Problem constants (from reference)
#define BB   4
#define NN   40
#define TT   64
#define NIN  4
#define NEMB 32
#define NHID 64
#define NG   256   // 4*NHID
#define EPSW 1e-5f

__device__ __forceinline__ float fast_sigmoid(float x) {
    return __fdividef(1.0f, 1.0f + __expf(-x));
}
__device__ __forceinline__ float fast_tanh(float x) {
    return __fdividef(2.0f, 1.0f + __expf(-2.0f * x)) - 1.0f;
}

// ---------------------------------------------------------------------------
// Kernel 1: per-(b,n) LSTM chain + temporal-attention pooling (output cols 0..63)
// Grid: 160 blocks (b*40+n), 256 threads (one per gate row).
//
//  * __launch_bounds__(256, 1): round-3 showed VGPR_Count=48 — the compiler's
//    default occupancy heuristic (~8 waves/EU -> 64-VGPR cap) was evicting the
//    64-float W_hh row from registers and re-fetching it every serial step
//    (~1700 cyc/step, VALUBusy 14%). We only run 1 block/CU (160 blocks on
//    256 CUs), so demand min-waves-per-EU=1 and let VGPRs go to ~100+.
//  * W_hh row held in 16 NAMED float4 registers (no indexed array -> SROA
//    cannot fail, no scratch).
//  * embedding folded into gate weights: gx[t,g] = bc_g + x[t,:4].Wc[g,:4]
//    (Wc = W_ih @ W_emb), computed in-loop (4 FMAs). Loop stays ROLLED
//    (round-2's full unroll caused I-cache thrash: 8K-instr body).
//  * ONE barrier per step; redundant c/h update in every wave (bit-identical,
//    racing identical-value s_h writes benign); s_act double-buffered.
//  * no global stores inside the serial loop (hs dumped from LDS at the end).
// ---------------------------------------------------------------------------
__global__ __launch_bounds__(256, 1)
void k_lstm(const float* __restrict__ inputs,
            const float* __restrict__ W_emb,
            const float* __restrict__ b_emb,
            const float* __restrict__ W_ih,
            const float* __restrict__ W_hh,
            const float* __restrict__ b_ih,
            const float* __restrict__ b_hh,
            const float* __restrict__ W_att,
            float* __restrict__ out,
            float* __restrict__ hs_g)
{
    __shared__ __align__(16) float s_x[TT * NIN];          // raw inputs (t-major)
    __shared__ __align__(16) float s_h[NHID];              // current hidden state
    __shared__ __align__(16) float s_act[2][NG];           // gate acts, double-buffered
    __shared__ __align__(16) float s_hs[TT * (NHID + 1)];  // all h, pad 65
    __shared__ __align__(16) float s_war[NHID];            // W_att[0,64:128]
    __shared__ __align__(16) float s_p[TT];                // softmax weights

    const int m   = blockIdx.x;       // b*NN + n
    const int tid = threadIdx.x;
    const int g   = tid;              // gate row 0..255
    const int j   = tid & 63;         // hidden index this thread updates
    const int gtype = g >> 6;         // 0:i 1:f 2:g 3:o (wave-uniform)

    // stage raw inputs (256 floats, coalesced)
    s_x[tid] = inputs[m * (TT * NIN) + tid];
    if (tid < NHID) { s_war[tid] = W_att[NHID + tid]; s_h[tid] = 0.0f; }

    // ---- fold embedding into this thread's gate row: Wc[4], bc ----
    float wcx = 0.f, wcy = 0.f, wcz = 0.f, wcw = 0.f;
    float bc  = b_ih[g] + b_hh[g];
    {
        const float4* wih4  = (const float4*)(W_ih + g * NEMB);
        const float4* wemb4 = (const float4*)W_emb;   // row e (4 floats)
        #pragma unroll
        for (int e4 = 0; e4 < NEMB / 4; ++e4) {
            float4 wv = wih4[e4];
            float4 m0 = wemb4[4 * e4 + 0];
            float4 m1 = wemb4[4 * e4 + 1];
            float4 m2 = wemb4[4 * e4 + 2];
            float4 m3 = wemb4[4 * e4 + 3];
            wcx += wv.x * m0.x + wv.y * m1.x + wv.z * m2.x + wv.w * m3.x;
            wcy += wv.x * m0.y + wv.y * m1.y + wv.z * m2.y + wv.w * m3.y;
            wcz += wv.x * m0.z + wv.y * m1.z + wv.z * m2.z + wv.w * m3.z;
            wcw += wv.x * m0.w + wv.y * m1.w + wv.z * m2.w + wv.w * m3.w;
            bc  += wv.x * b_emb[4 * e4 + 0] + wv.y * b_emb[4 * e4 + 1]
                 + wv.z * b_emb[4 * e4 + 2] + wv.w * b_emb[4 * e4 + 3];
        }
    }

    // ---- this thread's recurrent weight row: 16 NAMED float4 registers ----
    const float4* q4 = (const float4*)(W_hh + g * NHID);
    const float4 w0 = q4[0],  w1 = q4[1],  w2 = q4[2],  w3 = q4[3];
    const float4 w4 = q4[4],  w5 = q4[5],  w6 = q4[6],  w7 = q4[7];
    const float4 w8 = q4[8],  w9 = q4[9],  wA = q4[10], wB = q4[11];
    const float4 wC = q4[12], wD = q4[13], wE = q4[14], wF = q4[15];

    __syncthreads();   // s_x, s_h ready

    // ---- recurrence: 64 steps, ONE barrier each, ROLLED loop ----
    float c = 0.0f;    // redundant per-wave copy of c_j
    #pragma unroll 1
    for (int t = 0; t < TT; ++t) {
        const int p = t & 1;
        // gate pre-activation: bc + x[t].wc + h . whh  (4 independent chains)
        const float4 x = ((const float4*)s_x)[t];       // LDS broadcast
        float v0 = bc + x.x * wcx + x.y * wcy;
        float v1 = x.z * wcz + x.w * wcw;
        float v2 = 0.f, v3 = 0.f;
        const float4* h4 = (const float4*)s_h;
        #define DOT4(W, K) { float4 a = h4[K];            \
            v0 += a.x * W.x; v1 += a.y * W.y;             \
            v2 += a.z * W.z; v3 += a.w * W.w; }
        DOT4(w0, 0)  DOT4(w1, 1)  DOT4(w2, 2)  DOT4(w3, 3)
        DOT4(w4, 4)  DOT4(w5, 5)  DOT4(w6, 6)  DOT4(w7, 7)
        DOT4(w8, 8)  DOT4(w9, 9)  DOT4(wA, 10) DOT4(wB, 11)
        DOT4(wC, 12) DOT4(wD, 13) DOT4(wE, 14) DOT4(wF, 15)
        #undef DOT4
        const float v = (v0 + v1) + (v2 + v3);
        const float a = (gtype == 2) ? fast_tanh(v) : fast_sigmoid(v);
        s_act[p][g] = a;
        __syncthreads();

        // redundant update in every wave (bit-identical across waves)
        const float ig = s_act[p][j];
        const float fg = s_act[p][NHID + j];
        const float gg = s_act[p][2 * NHID + j];
        const float og = s_act[p][3 * NHID + j];
        c = fg * c + ig * gg;
        const float h = og * fast_tanh(c);
        s_h[j] = h;                                   // identical values race: benign
        if (tid < NHID) s_hs[t * (NHID + 1) + j] = h; // wave 0 records history
        asm volatile("" ::: "memory");  // compiler fence: no read hoist over the write
        // no 2nd barrier: each wave reads back its OWN s_h writes next step;
        // other waves' writes are identical 32-bit values.
    }
    __syncthreads();   // s_hs complete

    // ---- dump hs to global for kernel 2 (coalesced) ----
    #pragma unroll
    for (int idx = tid; idx < TT * NHID; idx += 256) {
        const int t = idx >> 6, h = idx & 63;
        hs_g[m * (TT * NHID) + idx] = s_hs[t * (NHID + 1) + h];
    }

    // ---- temporal attention pooling (softmax over t, i-independent) ----
    if (tid < TT) {
        const int t = tid;
        float r = 0.0f;
        #pragma unroll
        for (int k = 0; k < NHID; ++k)
            r += s_hs[t * (NHID + 1) + k] * s_war[k];
        float mx = r;
        #pragma unroll
        for (int off = 32; off >= 1; off >>= 1)
            mx = fmaxf(mx, __shfl_xor(mx, off));
        const float e = __expf(r - mx);
        float s = e;
        #pragma unroll
        for (int off = 32; off >= 1; off >>= 1)
            s += __shfl_xor(s, off);
        s_p[t] = __fdividef(e, s);
    }
    __syncthreads();

    if (tid < NHID) {
        float acc = 0.0f;
        #pragma unroll
        for (int t = 0; t < TT; ++t)
            acc += s_p[t] * s_hs[t * (NHID + 1) + tid];
        out[m * (2 * NHID) + tid] = fast_tanh(acc);
    }
}

// ---------------------------------------------------------------------------
// Kernel 2: spatial inverse-distance aggregation (output cols 64..127)
// chsum[b,i,h] = sum_t sum_{j!=i} hs[b,j,t,h] / (dist(i,j,t)+eps)
// Grid: 160 blocks (b*40+i), 256 threads = (t-quarter q, h).
// ---------------------------------------------------------------------------
__global__ __launch_bounds__(256)
void k_spatial(const float* __restrict__ inputs,
               const float* __restrict__ hs_g,
               float* __restrict__ out)
{
    __shared__ float s_w[TT * NN];          // 2560 inverse-distance weights
    __shared__ float s_part[4 * NHID];

    const int bi  = blockIdx.x;
    const int b   = bi / NN;
    const int i   = bi - b * NN;
    const int tid = threadIdx.x;

    for (int idx = tid; idx < TT * NN; idx += 256) {
        const int t = idx / NN;
        const int j = idx - t * NN;
        const float* pi = inputs + ((b * NN + i) * TT + t) * NIN;
        const float* pj = inputs + ((b * NN + j) * TT + t) * NIN;
        const float dx = pi[0] - pj[0];
        const float dy = pi[1] - pj[1];
        const float d  = sqrtf(dx * dx + dy * dy);
        s_w[idx] = (j == i) ? 0.0f : __fdividef(1.0f, d + EPSW);
    }
    __syncthreads();

    const int h = tid & 63;
    const int q = tid >> 6;          // t-quarter

    const float* base = hs_g + (size_t)b * NN * TT * NHID + h;
    float a0 = 0.f, a1 = 0.f, a2 = 0.f, a3 = 0.f;
    for (int t = q * 16; t < q * 16 + 16; ++t) {
        const float* hp = base + t * NHID;
        const float* wp = s_w + t * NN;
        #pragma unroll
        for (int j = 0; j < NN; j += 4) {
            a0 += wp[j + 0] * hp[(size_t)(j + 0) * TT * NHID];
            a1 += wp[j + 1] * hp[(size_t)(j + 1) * TT * NHID];
            a2 += wp[j + 2] * hp[(size_t)(j + 2) * TT * NHID];
            a3 += wp[j + 3] * hp[(size_t)(j + 3) * TT * NHID];
        }
    }
    s_part[q * NHID + h] = (a0 + a1) + (a2 + a3);
    __syncthreads();

    if (tid < NHID) {
        const float s = s_part[tid] + s_part[NHID + tid] +
                        s_part[2 * NHID + tid] + s_part[3 * NHID + tid];
        out[bi * (2 * NHID) + NHID + tid] = fast_tanh(s);
    }
}

extern "C" void kernel_launch(void* const* d_in, const int* in_sizes, int n_in,
                              void* d_out, int out_size, void* d_ws, size_t ws_size,
                              hipStream_t stream) {
    const float* inputs = (const float*)d_in[0];
    // d_in[1..4]: rel_rec / rel_send / rel_rec_t / rel_send_t (one-hot, folded)
    const float* W_emb  = (const float*)d_in[5];
    const float* b_emb  = (const float*)d_in[6];
    const float* W_ih   = (const float*)d_in[7];
    const float* W_hh   = (const float*)d_in[8];
    const float* b_ih   = (const float*)d_in[9];
    const float* b_hh   = (const float*)d_in[10];
    const float* W_att  = (const float*)d_in[11];
    // d_in[12] = b_att: cancels in the softmax, unused.

    float* outp = (float*)d_out;
    float* hs_g = (float*)d_ws;   // 160*64*64 floats = 2.62 MB

    hipLaunchKernelGGL(k_lstm, dim3(BB * NN), dim3(256), 0, stream,
                       inputs, W_emb, b_emb, W_ih, W_hh, b_ih, b_hh, W_att,
                       outp, hs_g);
    hipLaunchKernelGGL(k_spatial, dim3(BB * NN), dim3(256), 0, stream,
                       inputs, hs_g, outp);
}

// Round 5
// 135.219 us; speedup vs baseline: 1.0252x; 1.0252x over previous
//
#include <hip/hip_runtime.h>
#include <math.h>

// Problem constants (from reference)
#define BB   4
#define NN   40
#define TT   64
#define NIN  4
#define NEMB 32
#define NHID 64
#define NG   256   // 4*NHID
#define EPSW 1e-5f

__device__ __forceinline__ float fast_sigmoid(float x) {
    return __fdividef(1.0f, 1.0f + __expf(-x));
}
__device__ __forceinline__ float fast_tanh(float x) {
    return __fdividef(2.0f, 1.0f + __expf(-2.0f * x)) - 1.0f;
}
// broadcast lane l's value of v across the wave (uniform l -> v_readlane)
__device__ __forceinline__ float lanebcast(float v, int l) {
    return __int_as_float(__builtin_amdgcn_readlane(__float_as_int(v), l));
}

// ---------------------------------------------------------------------------
// Kernel 1: per-(b,n) LSTM chain + temporal attention pool (output cols 0..63)
// Grid: 160 blocks (b*40+n), 256 threads (one per gate row).
//
// History of this kernel (counters-driven):
//  * R2: full unroll of the 64-step loop -> I-cache thrash (FETCH +455KB,
//    VALUBusy 6.7%). Loop must stay ROLLED.
//  * R3/R4: VGPR_Count=48 both rounds => compiler SINKS the 64-float W_hh row
//    loads into the serial loop (live set across the barrier would need >=75
//    VGPRs). ~64 L1 dwordx4 + 64 ds_read_b128 per CU-step, unhideable at
//    1 wave/SIMD => ~1700 cyc/step. __launch_bounds__(256,1) raised the
//    budget but not the heuristic.
//  * R5 (this): (a) weights pinned via volatile asm (cannot be sunk/dup'd
//    into the loop -> must stay in VGPRs); (b) h kept REGISTER-distributed:
//    every wave redundantly updates h for j=lane, so readlane(h,k) replaces
//    all LDS reads of h. In-loop DS traffic: 1 b128 (x) + 1 write + 4 reads
//    (act exchange) per thread + 1 barrier.
// ---------------------------------------------------------------------------
__global__ __launch_bounds__(256, 1)
void k_lstm(const float* __restrict__ inputs,
            const float* __restrict__ W_emb,
            const float* __restrict__ b_emb,
            const float* __restrict__ W_ih,
            const float* __restrict__ W_hh,
            const float* __restrict__ b_ih,
            const float* __restrict__ b_hh,
            const float* __restrict__ W_att,
            float* __restrict__ out,
            float* __restrict__ hs_g)
{
    __shared__ __align__(16) float s_x[TT * NIN];          // raw inputs (t-major)
    __shared__ __align__(16) float s_act[2][NG];           // gate acts, double-buffered
    __shared__ __align__(16) float s_hs[TT * (NHID + 1)];  // h history, pad 65
    __shared__ __align__(16) float s_war[NHID];            // W_att[0,64:128]
    __shared__ __align__(16) float s_p[TT];                // softmax weights

    const int m   = blockIdx.x;       // b*NN + n
    const int tid = threadIdx.x;
    const int g   = tid;              // gate row 0..255
    const int j   = tid & 63;         // hidden index this thread updates (lane)
    const int gtype = g >> 6;         // 0:i 1:f 2:g 3:o (wave-uniform)

    // stage raw inputs (256 floats, coalesced)
    s_x[tid] = inputs[m * (TT * NIN) + tid];
    if (tid < NHID) s_war[tid] = W_att[NHID + tid];

    // ---- fold embedding into this thread's gate row: Wc[4], bc ----
    float wcx = 0.f, wcy = 0.f, wcz = 0.f, wcw = 0.f;
    float bc  = b_ih[g] + b_hh[g];
    {
        const float4* wih4  = (const float4*)(W_ih + g * NEMB);
        const float4* wemb4 = (const float4*)W_emb;   // row e (4 floats)
        #pragma unroll
        for (int e4 = 0; e4 < NEMB / 4; ++e4) {
            float4 wv = wih4[e4];
            float4 m0 = wemb4[4 * e4 + 0];
            float4 m1 = wemb4[4 * e4 + 1];
            float4 m2 = wemb4[4 * e4 + 2];
            float4 m3 = wemb4[4 * e4 + 3];
            wcx += wv.x * m0.x + wv.y * m1.x + wv.z * m2.x + wv.w * m3.x;
            wcy += wv.x * m0.y + wv.y * m1.y + wv.z * m2.y + wv.w * m3.y;
            wcz += wv.x * m0.z + wv.y * m1.z + wv.z * m2.z + wv.w * m3.z;
            wcw += wv.x * m0.w + wv.y * m1.w + wv.z * m2.w + wv.w * m3.w;
            bc  += wv.x * b_emb[4 * e4 + 0] + wv.y * b_emb[4 * e4 + 1]
                 + wv.z * b_emb[4 * e4 + 2] + wv.w * b_emb[4 * e4 + 3];
        }
    }

    // ---- recurrent weight row: 16 float4 regs, PINNED so the compiler
    //      cannot sink the loads back into the serial loop (R3/R4 bug) ----
    const float4* q4 = (const float4*)(W_hh + g * NHID);
    float4 w0 = q4[0],  w1 = q4[1],  w2 = q4[2],  w3 = q4[3];
    float4 w4 = q4[4],  w5 = q4[5],  w6 = q4[6],  w7 = q4[7];
    float4 w8 = q4[8],  w9 = q4[9],  wA = q4[10], wB = q4[11];
    float4 wC = q4[12], wD = q4[13], wE = q4[14], wF = q4[15];
    #define PIN4(W) asm volatile("" : "+v"(W.x), "+v"(W.y), "+v"(W.z), "+v"(W.w))
    PIN4(w0); PIN4(w1); PIN4(w2); PIN4(w3);
    PIN4(w4); PIN4(w5); PIN4(w6); PIN4(w7);
    PIN4(w8); PIN4(w9); PIN4(wA); PIN4(wB);
    PIN4(wC); PIN4(wD); PIN4(wE); PIN4(wF);
    #undef PIN4

    __syncthreads();   // s_x ready

    // ---- recurrence: 64 steps, ONE barrier each, ROLLED loop ----
    // h for index j=lane lives in a register, redundantly in every wave;
    // readlane(h,k) gives the full h-vector to the dot product (no DS pipe).
    float c = 0.0f, h = 0.0f;
    #pragma unroll 1
    for (int t = 0; t < TT; ++t) {
        const int p = t & 1;
        const float4 x = ((const float4*)s_x)[t];       // LDS broadcast (1 b128)

        float v0 = bc, v1 = 0.f, v2 = 0.f, v3 = 0.f;
        #define DOT4(W, K) {                                  \
            v0 += lanebcast(h, 4*(K)+0) * W.x;                \
            v1 += lanebcast(h, 4*(K)+1) * W.y;                \
            v2 += lanebcast(h, 4*(K)+2) * W.z;                \
            v3 += lanebcast(h, 4*(K)+3) * W.w; }
        DOT4(w0, 0)  DOT4(w1, 1)  DOT4(w2, 2)  DOT4(w3, 3)
        DOT4(w4, 4)  DOT4(w5, 5)  DOT4(w6, 6)  DOT4(w7, 7)
        DOT4(w8, 8)  DOT4(w9, 9)  DOT4(wA, 10) DOT4(wB, 11)
        DOT4(wC, 12) DOT4(wD, 13) DOT4(wE, 14) DOT4(wF, 15)
        #undef DOT4
        const float vx = x.x * wcx + x.y * wcy + x.z * wcz + x.w * wcw;
        const float v  = ((v0 + v1) + (v2 + v3)) + vx;

        const float a = (gtype == 2) ? fast_tanh(v) : fast_sigmoid(v);
        s_act[p][g] = a;
        __syncthreads();

        // redundant update in every wave (bit-identical across waves)
        const float ig = s_act[p][j];
        const float fg = s_act[p][NHID + j];
        const float gg = s_act[p][2 * NHID + j];
        const float og = s_act[p][3 * NHID + j];
        c = fg * c + ig * gg;
        h = og * fast_tanh(c);
        if (gtype == 0) s_hs[t * (NHID + 1) + j] = h;   // wave 0 records history
        // no 2nd barrier: s_act double-buffered by p; h is in registers.
    }
    __syncthreads();   // s_hs complete

    // ---- dump hs to global for kernel 2 (coalesced) ----
    #pragma unroll
    for (int idx = tid; idx < TT * NHID; idx += 256) {
        const int t = idx >> 6, hh = idx & 63;
        hs_g[m * (TT * NHID) + idx] = s_hs[t * (NHID + 1) + hh];
    }

    // ---- temporal attention pooling (softmax over t, i-independent) ----
    if (tid < TT) {
        const int t = tid;
        float r = 0.0f;
        #pragma unroll
        for (int k = 0; k < NHID; ++k)
            r += s_hs[t * (NHID + 1) + k] * s_war[k];
        float mx = r;
        #pragma unroll
        for (int off = 32; off >= 1; off >>= 1)
            mx = fmaxf(mx, __shfl_xor(mx, off));
        const float e = __expf(r - mx);
        float s = e;
        #pragma unroll
        for (int off = 32; off >= 1; off >>= 1)
            s += __shfl_xor(s, off);
        s_p[t] = __fdividef(e, s);
    }
    __syncthreads();

    if (tid < NHID) {
        float acc = 0.0f;
        #pragma unroll
        for (int t = 0; t < TT; ++t)
            acc += s_p[t] * s_hs[t * (NHID + 1) + tid];
        out[m * (2 * NHID) + tid] = fast_tanh(acc);
    }
}

// ---------------------------------------------------------------------------
// Kernel 2: spatial inverse-distance aggregation (output cols 64..127)
// chsum[b,i,h] = sum_t sum_{j!=i} hs[b,j,t,h] / (dist(i,j,t)+eps)
// Grid: 160 blocks (b*40+i), 256 threads = (t-quarter q, h).
// ---------------------------------------------------------------------------
__global__ __launch_bounds__(256)
void k_spatial(const float* __restrict__ inputs,
               const float* __restrict__ hs_g,
               float* __restrict__ out)
{
    __shared__ float s_w[TT * NN];          // 2560 inverse-distance weights
    __shared__ float s_part[4 * NHID];

    const int bi  = blockIdx.x;
    const int b   = bi / NN;
    const int i   = bi - b * NN;
    const int tid = threadIdx.x;

    for (int idx = tid; idx < TT * NN; idx += 256) {
        const int t = idx / NN;
        const int j = idx - t * NN;
        const float* pi = inputs + ((b * NN + i) * TT + t) * NIN;
        const float* pj = inputs + ((b * NN + j) * TT + t) * NIN;
        const float dx = pi[0] - pj[0];
        const float dy = pi[1] - pj[1];
        const float d  = sqrtf(dx * dx + dy * dy);
        s_w[idx] = (j == i) ? 0.0f : __fdividef(1.0f, d + EPSW);
    }
    __syncthreads();

    const int h = tid & 63;
    const int q = tid >> 6;          // t-quarter

    const float* base = hs_g + (size_t)b * NN * TT * NHID + h;
    float a0 = 0.f, a1 = 0.f, a2 = 0.f, a3 = 0.f;
    for (int t = q * 16; t < q * 16 + 16; ++t) {
        const float* hp = base + t * NHID;
        const float* wp = s_w + t * NN;
        #pragma unroll
        for (int j = 0; j < NN; j += 4) {
            a0 += wp[j + 0] * hp[(size_t)(j + 0) * TT * NHID];
            a1 += wp[j + 1] * hp[(size_t)(j + 1) * TT * NHID];
            a2 += wp[j + 2] * hp[(size_t)(j + 2) * TT * NHID];
            a3 += wp[j + 3] * hp[(size_t)(j + 3) * TT * NHID];
        }
    }
    s_part[q * NHID + h] = (a0 + a1) + (a2 + a3);
    __syncthreads();

    if (tid < NHID) {
        const float s = s_part[tid] + s_part[NHID + tid] +
                        s_part[2 * NHID + tid] + s_part[3 * NHID + tid];
        out[bi * (2 * NHID) + NHID + tid] = fast_tanh(s);
    }
}

extern "C" void kernel_launch(void* const* d_in, const int* in_sizes, int n_in,
                              void* d_out, int out_size, void* d_ws, size_t ws_size,
                              hipStream_t stream) {
    const float* inputs = (const float*)d_in[0];
    // d_in[1..4]: rel_rec / rel_send / rel_rec_t / rel_send_t (one-hot, folded)
    const float* W_emb  = (const float*)d_in[5];
    const float* b_emb  = (const float*)d_in[6];
    const float* W_ih   = (const float*)d_in[7];
    const float* W_hh   = (const float*)d_in[8];
    const float* b_ih   = (const float*)d_in[9];
    const float* b_hh   = (const float*)d_in[10];
    const float* W_att  = (const float*)d_in[11];
    // d_in[12] = b_att: cancels in the softmax, unused.

    float* outp = (float*)d_out;
    float* hs_g = (float*)d_ws;   // 160*64*64 floats = 2.62 MB

    hipLaunchKernelGGL(k_lstm, dim3(BB * NN), dim3(256), 0, stream,
                       inputs, W_emb, b_emb, W_ih, W_hh, b_ih, b_hh, W_att,
                       outp, hs_g);
    hipLaunchKernelGGL(k_spatial, dim3(BB * NN), dim3(256), 0, stream,
                       inputs, hs_g, outp);
}